// Round 2
// baseline (1502.980 us; speedup 1.0000x reference)
//
#include <hip/hip_runtime.h>
#include <hip/hip_bf16.h>

#define B_ 128
#define H_ 512
#define S_ 2048
#define ST 64          // s-tile per pass-1 block
#define NP (S_/ST)     // 32 partials per batch
#define RB 520         // LDS row stride (elements) for Bs: 16B-aligned rows

typedef short  bf16x8  __attribute__((ext_vector_type(8)));
typedef float  floatx4 __attribute__((ext_vector_type(4)));
typedef short  short4v __attribute__((ext_vector_type(4)));

__device__ __forceinline__ unsigned short f2bf(float f){
  unsigned u = __float_as_uint(f);
  unsigned r = (u + 0x7fffu + ((u >> 16) & 1u)) >> 16;   // RNE
  return (unsigned short)r;
}
__device__ __forceinline__ float bf2f(unsigned short h){
  return __uint_as_float(((unsigned)h) << 16);
}
__device__ __forceinline__ float fast_tanh(float x){
  x = fminf(15.f, fmaxf(-15.f, x));
  float e = __expf(2.f * x);
  return (e - 1.f) * __builtin_amdgcn_rcpf(e + 1.f);
}

// ---------------- k0: W_att fp32 -> bf16 ----------------
__global__ __launch_bounds__(256) void k_convW(const float* __restrict__ W,
                                               unsigned short* __restrict__ Wb){
  int i = (blockIdx.x * 256 + threadIdx.x) * 4;
  float4 v = *(const float4*)(W + i);
  short4v o;
  o[0] = (short)f2bf(v.x); o[1] = (short)f2bf(v.y);
  o[2] = (short)f2bf(v.z); o[3] = (short)f2bf(v.w);
  *(short4v*)(Wb + i) = o;
}

// ---------------- k_trans: hidden [B,H,S] fp32 -> hT [B,S,H] bf16 -----------
// grid (S/64, B). Lane = s; gathers 8 h (each h-row read coalesced 256B across
// the wave), writes one 16B chunk of the s-row. L2 write-back merges lines.
__global__ __launch_bounds__(256) void k_trans(const float* __restrict__ hidden,
                                               unsigned short* __restrict__ hT){
  const int tid = threadIdx.x, w = tid >> 6, l = tid & 63;
  const int b = blockIdx.y, s0 = blockIdx.x * 64;
  const float* src = hidden + (size_t)b * H_ * S_ + s0 + l;
  unsigned short* dst = hT + ((size_t)(b * S_) + s0 + l) * H_;
  #pragma unroll 4
  for (int it = 0; it < 16; ++it){
    int h0 = it * 32 + w * 8;
    bf16x8 pk;
    #pragma unroll
    for (int j = 0; j < 8; ++j)
      pk[j] = (short)f2bf(src[(size_t)(h0 + j) * S_]);
    *(bf16x8*)(dst + h0) = pk;
  }
}

// ======== shared epilogue code for pass1 (both variants) ====================
struct Pass1Shared {
  unsigned short Bs[ST * RB];
  float vatt[H_];
  float twav[4][ST];
  float ts[ST];
  float es[ST];
};

__device__ __forceinline__ void pass1_core(Pass1Shared& sh,
    const unsigned short* __restrict__ Wb,
    float* __restrict__ part_m, float* __restrict__ part_z,
    float* __restrict__ part_ctx, int b, int p)
{
  const int tid = threadIdx.x;
  const int w = tid >> 6, l = tid & 63;
  const int quad = l >> 4, l16 = l & 15;
  float tacc[4] = {0.f, 0.f, 0.f, 0.f};

  for (int o = 0; o < 2; ++o){
    const int htbase = w * 8 + o * 4;
    floatx4 acc[4][4];
    #pragma unroll
    for (int ti = 0; ti < 4; ++ti)
      #pragma unroll
      for (int ss = 0; ss < 4; ++ss){
        floatx4 z4 = {0.f, 0.f, 0.f, 0.f};
        acc[ti][ss] = z4;
      }

    for (int k0 = 0; k0 < H_; k0 += 32){
      bf16x8 a[4];
      #pragma unroll
      for (int ti = 0; ti < 4; ++ti)
        a[ti] = *(const bf16x8*)(Wb + ((htbase + ti) * 16 + l16) * H_ + k0 + quad * 8);
      bf16x8 bb[4];
      #pragma unroll
      for (int ss = 0; ss < 4; ++ss)
        bb[ss] = *(const bf16x8*)(&sh.Bs[(ss * 16 + l16) * RB + k0 + quad * 8]);
      #pragma unroll
      for (int ti = 0; ti < 4; ++ti)
        #pragma unroll
        for (int ss = 0; ss < 4; ++ss)
          acc[ti][ss] = __builtin_amdgcn_mfma_f32_16x16x32_bf16(a[ti], bb[ss], acc[ti][ss], 0, 0, 0);
    }

    #pragma unroll
    for (int ti = 0; ti < 4; ++ti){
      const int hbase = (htbase + ti) * 16 + quad * 4;
      #pragma unroll
      for (int r = 0; r < 4; ++r){
        float va = sh.vatt[hbase + r];
        #pragma unroll
        for (int ss = 0; ss < 4; ++ss)
          tacc[ss] += va * fast_tanh(acc[ti][ss][r]);
      }
    }
  }

  #pragma unroll
  for (int ss = 0; ss < 4; ++ss){
    tacc[ss] += __shfl_xor(tacc[ss], 16);
    tacc[ss] += __shfl_xor(tacc[ss], 32);
  }
  if (l < 16){
    #pragma unroll
    for (int ss = 0; ss < 4; ++ss) sh.twav[w][ss * 16 + l] = tacc[ss];
  }
  __syncthreads();
  if (tid < ST) sh.ts[tid] = sh.twav[0][tid] + sh.twav[1][tid] + sh.twav[2][tid] + sh.twav[3][tid];
  __syncthreads();

  float m = -1e30f;
  for (int s = 0; s < ST; ++s) m = fmaxf(m, sh.ts[s]);
  if (tid < ST) sh.es[tid] = __expf(sh.ts[tid] - m);
  __syncthreads();
  float z = 0.f;
  for (int s = 0; s < ST; ++s) z += sh.es[s];

  const int pidx = b * NP + p;
  if (tid == 0){ part_m[pidx] = m; part_z[pidx] = z; }

  for (int h = tid; h < H_; h += 256){
    float a = 0.f;
    for (int s = 0; s < ST; ++s) a += sh.es[s] * bf2f(sh.Bs[s * RB + h]);
    part_ctx[(size_t)pidx * H_ + h] = a;
  }
}

// ---------------- k_pass1_hT: stage from bf16 hT (vectorized) ---------------
__global__ __launch_bounds__(256, 2) void k_pass1_hT(
    const unsigned short* __restrict__ hT, const float* __restrict__ v_att,
    const unsigned short* __restrict__ Wb,
    float* __restrict__ part_m, float* __restrict__ part_z,
    float* __restrict__ part_ctx)
{
  __shared__ Pass1Shared sh;
  const int tid = threadIdx.x, w = tid >> 6, l = tid & 63;
  const int p = blockIdx.x & (NP - 1);
  const int b = blockIdx.x >> 5;
  const int s0 = p * ST;

  sh.vatt[tid]       = v_att[tid];
  sh.vatt[tid + 256] = v_att[tid + 256];

  const unsigned short* src = hT + (size_t)(b * S_ + s0) * H_;
  #pragma unroll
  for (int r = 0; r < 2; ++r){
    const int s = w * 16 + (l >> 3) * 2 + r;
    const unsigned short* row = src + (size_t)s * H_;
    #pragma unroll
    for (int i = 0; i < 8; ++i){
      const int c8 = ((l & 7) + 8 * i) * 8;
      bf16x8 v = *(const bf16x8*)(row + c8);
      *(bf16x8*)(&sh.Bs[s * RB + c8]) = v;
    }
  }
  __syncthreads();
  pass1_core(sh, Wb, part_m, part_z, part_ctx, b, p);
}

// ---------------- k_pass1_f32: fallback, stage from fp32 hidden -------------
__global__ __launch_bounds__(256, 2) void k_pass1_f32(
    const float* __restrict__ hidden, const float* __restrict__ v_att,
    const unsigned short* __restrict__ Wb,
    float* __restrict__ part_m, float* __restrict__ part_z,
    float* __restrict__ part_ctx)
{
  __shared__ Pass1Shared sh;
  const int tid = threadIdx.x, w = tid >> 6, l = tid & 63;
  const int p = blockIdx.x & (NP - 1);
  const int b = blockIdx.x >> 5;
  const int s0 = p * ST;

  sh.vatt[tid]       = v_att[tid];
  sh.vatt[tid + 256] = v_att[tid + 256];

  {
    const float* src0 = hidden + ((size_t)b * H_) * S_ + s0 + l;
    #pragma unroll
    for (int it = 0; it < 16; ++it){
      int kb = it * 32 + w * 8;
      const float* src = src0 + (size_t)kb * S_;
      bf16x8 pk;
      #pragma unroll
      for (int j = 0; j < 8; ++j)
        pk[j] = (short)f2bf(src[(size_t)j * S_]);
      *(bf16x8*)(&sh.Bs[l * RB + kb]) = pk;
    }
  }
  __syncthreads();
  pass1_core(sh, Wb, part_m, part_z, part_ctx, b, p);
}

// ---------------- k2: combine partials -> context -> 2-layer MLP ------------
__global__ __launch_bounds__(256) void k_mlp(
    const float* __restrict__ part_m, const float* __restrict__ part_z,
    const float* __restrict__ part_ctx,
    const float* __restrict__ fc1_w, const float* __restrict__ fc1_b,
    const float* __restrict__ fc2_w, const float* __restrict__ fc2_b,
    float* __restrict__ out2)
{
  __shared__ float ctx[H_];
  __shared__ float h1[H_];
  __shared__ float wp[NP];
  const int b = blockIdx.x, tid = threadIdx.x;

  float m = -1e30f;
  for (int pp = 0; pp < NP; ++pp) m = fmaxf(m, part_m[b * NP + pp]);
  if (tid < NP) wp[tid] = __expf(part_m[b * NP + tid] - m);
  __syncthreads();
  float z = 0.f;
  for (int pp = 0; pp < NP; ++pp) z += wp[pp] * part_z[b * NP + pp];
  float invz = 1.f / z;

  for (int h = tid; h < H_; h += 256){
    float a = 0.f;
    for (int pp = 0; pp < NP; ++pp) a += wp[pp] * part_ctx[(size_t)(b * NP + pp) * H_ + h];
    ctx[h] = a * invz;
  }
  __syncthreads();

  for (int i = tid; i < H_; i += 256){
    const float4* row = (const float4*)(fc1_w + (size_t)i * H_);
    float4 s4 = {0.f, 0.f, 0.f, 0.f};
    for (int j = 0; j < H_ / 4; ++j){
      float4 wv = row[j];
      s4.x += wv.x * ctx[4 * j];     s4.y += wv.y * ctx[4 * j + 1];
      s4.z += wv.z * ctx[4 * j + 2]; s4.w += wv.w * ctx[4 * j + 3];
    }
    h1[i] = fmaxf(fc1_b[i] + s4.x + s4.y + s4.z + s4.w, 0.f);
  }
  __syncthreads();

  for (int i = tid; i < H_; i += 256){
    const float4* row = (const float4*)(fc2_w + (size_t)i * H_);
    float4 s4 = {0.f, 0.f, 0.f, 0.f};
    for (int j = 0; j < H_ / 4; ++j){
      float4 wv = row[j];
      s4.x += wv.x * h1[4 * j];     s4.y += wv.y * h1[4 * j + 1];
      s4.z += wv.z * h1[4 * j + 2]; s4.w += wv.w * h1[4 * j + 3];
    }
    out2[(size_t)b * H_ + i] = fmaxf(fc2_b[i] + s4.x + s4.y + s4.z + s4.w, 0.f);
  }
}

// ---------------- k_probs_hT: one wave per s-row, bf16 reads ----------------
// grid (S/64, B). Lane owns h-slice [l*8, l*8+8); one 16B load per row.
__global__ __launch_bounds__(256) void k_probs_hT(
    const unsigned short* __restrict__ hT, const float* __restrict__ v_ptr,
    const float* __restrict__ out2, float* __restrict__ probs)
{
  const int tid = threadIdx.x, w = tid >> 6, l = tid & 63;
  const int b = blockIdx.y, s0 = blockIdx.x * 64;

  float vp[8], ob[8];
  {
    float4 a = *(const float4*)(v_ptr + l * 8);
    float4 c = *(const float4*)(v_ptr + l * 8 + 4);
    vp[0]=a.x; vp[1]=a.y; vp[2]=a.z; vp[3]=a.w;
    vp[4]=c.x; vp[5]=c.y; vp[6]=c.z; vp[7]=c.w;
    float4 d = *(const float4*)(out2 + (size_t)b * H_ + l * 8);
    float4 e = *(const float4*)(out2 + (size_t)b * H_ + l * 8 + 4);
    ob[0]=d.x; ob[1]=d.y; ob[2]=d.z; ob[3]=d.w;
    ob[4]=e.x; ob[5]=e.y; ob[6]=e.z; ob[7]=e.w;
  }

  const unsigned short* base = hT + (size_t)(b * S_ + s0) * H_ + l * 8;
  #pragma unroll 2
  for (int i = 0; i < 16; ++i){
    const int s = w * 16 + i;
    bf16x8 hv = *(const bf16x8*)(base + (size_t)s * H_);
    float acc = 0.f;
    #pragma unroll
    for (int j = 0; j < 8; ++j)
      acc += vp[j] * fast_tanh(bf2f((unsigned short)hv[j]) + ob[j]);
    acc += __shfl_xor(acc, 1);  acc += __shfl_xor(acc, 2);
    acc += __shfl_xor(acc, 4);  acc += __shfl_xor(acc, 8);
    acc += __shfl_xor(acc, 16); acc += __shfl_xor(acc, 32);
    if (l == 0) probs[(size_t)b * S_ + s0 + s] = acc;
  }
}

// ---------------- k_probs_f32: fallback ------------------------------------
__global__ __launch_bounds__(256) void k_probs_f32(
    const float* __restrict__ hidden, const float* __restrict__ v_ptr,
    const float* __restrict__ out2, float* __restrict__ probs)
{
  __shared__ float vp[H_], ob[H_];
  const int b = blockIdx.y, c = blockIdx.x, tid = threadIdx.x;
  vp[tid]       = v_ptr[tid];
  vp[tid + 256] = v_ptr[tid + 256];
  ob[tid]       = out2[(size_t)b * H_ + tid];
  ob[tid + 256] = out2[(size_t)b * H_ + tid + 256];
  __syncthreads();

  const int s = c * 512 + tid * 2;
  const float* base = hidden + (size_t)b * H_ * S_ + s;
  float a0 = 0.f, a1 = 0.f;
  #pragma unroll 4
  for (int h = 0; h < H_; ++h){
    float2 hv = *(const float2*)(base + (size_t)h * S_);
    float wv = vp[h], o = ob[h];
    a0 += wv * fast_tanh(hv.x + o);
    a1 += wv * fast_tanh(hv.y + o);
  }
  probs[(size_t)b * S_ + s]     = a0;
  probs[(size_t)b * S_ + s + 1] = a1;
}

// ---------------- launcher ----------------
extern "C" void kernel_launch(void* const* d_in, const int* in_sizes, int n_in,
                              void* d_out, int out_size, void* d_ws, size_t ws_size,
                              hipStream_t stream)
{
  const float* hidden = (const float*)d_in[0];
  const float* v_att  = (const float*)d_in[1];
  const float* W_att  = (const float*)d_in[2];
  const float* v_ptr  = (const float*)d_in[3];
  const float* fc1_w  = (const float*)d_in[4];
  const float* fc1_b  = (const float*)d_in[5];
  const float* fc2_w  = (const float*)d_in[6];
  const float* fc2_b  = (const float*)d_in[7];
  float* probs = (float*)d_out;

  char* ws = (char*)d_ws;
  unsigned short* Wb = (unsigned short*)ws;                        // 512 KiB
  float* part_m   = (float*)(ws + (512u<<10));                     // 16 KiB
  float* part_z   = (float*)(ws + (512u<<10) + (16u<<10));         // 16 KiB
  float* part_ctx = (float*)(ws + (512u<<10) + (32u<<10));         // 8 MiB
  float* out2     = (float*)(ws + (512u<<10) + (32u<<10) + (8u<<20)); // 256 KiB
  unsigned short* hT = (unsigned short*)(ws + (16u<<20));          // 256 MiB

  const size_t need = (16u<<20) + ((size_t)B_ * S_ * H_ * 2);

  hipLaunchKernelGGL(k_convW, dim3(256), dim3(256), 0, stream, W_att, Wb);

  if (ws_size >= need){
    hipLaunchKernelGGL(k_trans, dim3(S_/64, B_), dim3(256), 0, stream, hidden, hT);
    hipLaunchKernelGGL(k_pass1_hT, dim3(B_ * NP), dim3(256), 0, stream,
                       hT, v_att, Wb, part_m, part_z, part_ctx);
    hipLaunchKernelGGL(k_mlp, dim3(B_), dim3(256), 0, stream,
                       part_m, part_z, part_ctx, fc1_w, fc1_b, fc2_w, fc2_b, out2);
    hipLaunchKernelGGL(k_probs_hT, dim3(S_/64, B_), dim3(256), 0, stream,
                       hT, v_ptr, out2, probs);
  } else {
    hipLaunchKernelGGL(k_pass1_f32, dim3(B_ * NP), dim3(256), 0, stream,
                       hidden, v_att, Wb, part_m, part_z, part_ctx);
    hipLaunchKernelGGL(k_mlp, dim3(B_), dim3(256), 0, stream,
                       part_m, part_z, part_ctx, fc1_w, fc1_b, fc2_w, fc2_b, out2);
    hipLaunchKernelGGL(k_probs_f32, dim3(4, B_), dim3(256), 0, stream,
                       hidden, v_ptr, out2, probs);
  }
}

// Round 3
// 1039.316 us; speedup vs baseline: 1.4461x; 1.4461x over previous
//
#include <hip/hip_runtime.h>
#include <hip/hip_bf16.h>

#define B_ 128
#define H_ 512
#define S_ 2048
#define ST 64          // s-tile per pass-1 block
#define NP (S_/ST)     // 32 partials per batch

typedef short  bf16x8  __attribute__((ext_vector_type(8)));
typedef float  floatx4 __attribute__((ext_vector_type(4)));
typedef short  short4v __attribute__((ext_vector_type(4)));

__device__ __forceinline__ unsigned short f2bf(float f){
  unsigned u = __float_as_uint(f);
  unsigned r = (u + 0x7fffu + ((u >> 16) & 1u)) >> 16;   // RNE
  return (unsigned short)r;
}
__device__ __forceinline__ float bf2f(unsigned short h){
  return __uint_as_float(((unsigned)h) << 16);
}
__device__ __forceinline__ float fast_tanh(float x){
  x = fminf(15.f, fmaxf(-15.f, x));
  float e = __expf(2.f * x);
  return (e - 1.f) * __builtin_amdgcn_rcpf(e + 1.f);
}
// XOR swizzle: row-stride 512 elems (no pad); 16B chunk c of row s lives at
// phys = (c & 56) | ((c ^ s) & 7). Conflict-free for row-writes, frag-reads,
// column-reads, and row-readback (only s&7 matters).
__device__ __forceinline__ int swz(int s, int c){
  return (c & 56) | ((c ^ s) & 7);
}

// ---------------- k0: W_att fp32 -> bf16 ----------------
__global__ __launch_bounds__(256) void k_convW(const float* __restrict__ W,
                                               unsigned short* __restrict__ Wb){
  int i = (blockIdx.x * 256 + threadIdx.x) * 4;
  float4 v = *(const float4*)(W + i);
  short4v o;
  o[0] = (short)f2bf(v.x); o[1] = (short)f2bf(v.y);
  o[2] = (short)f2bf(v.z); o[3] = (short)f2bf(v.w);
  *(short4v*)(Wb + i) = o;
}

// ---------------- k_pass1: stage + scores GEMM + tanh.v + partial softmax ---
// grid = B*NP blocks of 512 (8 waves). Wave w owns h-rows [w*64, w*64+64).
// Also writes the bf16 transposed tile to hT (coalesced) for k_probs.
template<int WRITE_HT>
__global__ __launch_bounds__(512, 4) void k_pass1(
    const float* __restrict__ hidden, const float* __restrict__ v_att,
    const unsigned short* __restrict__ Wb,
    float* __restrict__ part_m, float* __restrict__ part_z,
    float* __restrict__ part_ctx, unsigned short* __restrict__ hT)
{
  __shared__ unsigned short Bs[ST * 512];   // 64 KiB, swizzled
  __shared__ float vatt[H_];
  __shared__ float twav[8][ST];
  __shared__ float ts[ST];
  __shared__ float es[ST];

  const int tid = threadIdx.x;
  const int w = tid >> 6, l = tid & 63;
  const int p = blockIdx.x & (NP - 1);
  const int b = blockIdx.x >> 5;          // NP == 32
  const int s0 = p * ST;

  vatt[tid] = v_att[tid];

  // Stage hidden[b, :, s0:s0+64] -> bf16 LDS [s][k] (swizzled).
  // Thread: row s=l, 8 chunks c = w + it*8; each chunk = 8 h, stride-S gather
  // (coalesced 256B across the wave per h-row). Nontemporal: keep Wb L2-hot.
  {
    const float* src0 = hidden + ((size_t)b * H_) * S_ + s0 + l;
    #pragma unroll
    for (int it = 0; it < 8; ++it){
      const int c = w + it * 8;
      const float* src = src0 + (size_t)(c * 8) * S_;
      bf16x8 pk;
      #pragma unroll
      for (int j = 0; j < 8; ++j)
        pk[j] = (short)f2bf(__builtin_nontemporal_load(src + (size_t)j * S_));
      *(bf16x8*)(&Bs[l * 512 + swz(l, c) * 8]) = pk;
    }
  }
  __syncthreads();

  // Coalesced hT writeback: wave w rows s=w*8+r; lane l -> logical chunk l.
  if (WRITE_HT){
    #pragma unroll
    for (int r = 0; r < 8; ++r){
      const int s = w * 8 + r;
      bf16x8 v = *(const bf16x8*)(&Bs[s * 512 + swz(s, l) * 8]);
      __builtin_nontemporal_store(v,
          (bf16x8*)(hT + ((size_t)(b * S_) + s0 + s) * H_ + l * 8));
    }
  }

  const int quad = l >> 4, l16 = l & 15;
  float tacc[4] = {0.f, 0.f, 0.f, 0.f};

  {
    floatx4 acc[4][4];
    #pragma unroll
    for (int ti = 0; ti < 4; ++ti)
      #pragma unroll
      for (int ss = 0; ss < 4; ++ss){
        floatx4 z4 = {0.f, 0.f, 0.f, 0.f};
        acc[ti][ss] = z4;
      }

    for (int k0 = 0; k0 < H_; k0 += 32){
      bf16x8 a[4];
      #pragma unroll
      for (int ti = 0; ti < 4; ++ti)
        a[ti] = *(const bf16x8*)(Wb + ((w * 4 + ti) * 16 + l16) * H_ + k0 + quad * 8);
      bf16x8 bb[4];
      #pragma unroll
      for (int ss = 0; ss < 4; ++ss){
        const int c = (k0 >> 3) + quad;
        bb[ss] = *(const bf16x8*)(&Bs[(ss * 16 + l16) * 512 + swz(l16, c) * 8]);
      }
      #pragma unroll
      for (int ti = 0; ti < 4; ++ti)
        #pragma unroll
        for (int ss = 0; ss < 4; ++ss)
          acc[ti][ss] = __builtin_amdgcn_mfma_f32_16x16x32_bf16(a[ti], bb[ss], acc[ti][ss], 0, 0, 0);
    }

    // t[s] += v_att[h] * tanh(score[h][s]); C layout col=l16 (s), row=quad*4+r.
    #pragma unroll
    for (int ti = 0; ti < 4; ++ti){
      const int hbase = (w * 4 + ti) * 16 + quad * 4;
      #pragma unroll
      for (int r = 0; r < 4; ++r){
        float va = vatt[hbase + r];
        #pragma unroll
        for (int ss = 0; ss < 4; ++ss)
          tacc[ss] += va * fast_tanh(acc[ti][ss][r]);
      }
    }
  }

  #pragma unroll
  for (int ss = 0; ss < 4; ++ss){
    tacc[ss] += __shfl_xor(tacc[ss], 16);
    tacc[ss] += __shfl_xor(tacc[ss], 32);
  }
  if (l < 16){
    #pragma unroll
    for (int ss = 0; ss < 4; ++ss) twav[w][ss * 16 + l] = tacc[ss];
  }
  __syncthreads();
  if (tid < ST){
    float a = 0.f;
    #pragma unroll
    for (int ww = 0; ww < 8; ++ww) a += twav[ww][tid];
    ts[tid] = a;
  }
  __syncthreads();

  float m = -1e30f;
  for (int s = 0; s < ST; ++s) m = fmaxf(m, ts[s]);
  if (tid < ST) es[tid] = __expf(ts[tid] - m);
  __syncthreads();
  float z = 0.f;
  for (int s = 0; s < ST; ++s) z += es[s];

  const int pidx = b * NP + p;
  if (tid == 0){ part_m[pidx] = m; part_z[pidx] = z; }

  // Partial (unnormalized) context; h = tid (512 threads = H).
  {
    const int c = tid >> 3, e = tid & 7;
    float a = 0.f;
    for (int s = 0; s < ST; ++s)
      a += es[s] * bf2f(Bs[s * 512 + swz(s, c) * 8 + e]);
    part_ctx[(size_t)pidx * H_ + tid] = a;
  }
}

// ---------------- k2: combine partials -> context -> 2-layer MLP ------------
__global__ __launch_bounds__(256) void k_mlp(
    const float* __restrict__ part_m, const float* __restrict__ part_z,
    const float* __restrict__ part_ctx,
    const float* __restrict__ fc1_w, const float* __restrict__ fc1_b,
    const float* __restrict__ fc2_w, const float* __restrict__ fc2_b,
    float* __restrict__ out2)
{
  __shared__ float ctx[H_];
  __shared__ float h1[H_];
  __shared__ float wp[NP];
  const int b = blockIdx.x, tid = threadIdx.x;

  float m = -1e30f;
  for (int pp = 0; pp < NP; ++pp) m = fmaxf(m, part_m[b * NP + pp]);
  if (tid < NP) wp[tid] = __expf(part_m[b * NP + tid] - m);
  __syncthreads();
  float z = 0.f;
  for (int pp = 0; pp < NP; ++pp) z += wp[pp] * part_z[b * NP + pp];
  float invz = 1.f / z;

  for (int h = tid; h < H_; h += 256){
    float a = 0.f;
    for (int pp = 0; pp < NP; ++pp) a += wp[pp] * part_ctx[(size_t)(b * NP + pp) * H_ + h];
    ctx[h] = a * invz;
  }
  __syncthreads();

  for (int i = tid; i < H_; i += 256){
    const float4* row = (const float4*)(fc1_w + (size_t)i * H_);
    float4 s4 = {0.f, 0.f, 0.f, 0.f};
    for (int j = 0; j < H_ / 4; ++j){
      float4 wv = row[j];
      s4.x += wv.x * ctx[4 * j];     s4.y += wv.y * ctx[4 * j + 1];
      s4.z += wv.z * ctx[4 * j + 2]; s4.w += wv.w * ctx[4 * j + 3];
    }
    h1[i] = fmaxf(fc1_b[i] + s4.x + s4.y + s4.z + s4.w, 0.f);
  }
  __syncthreads();

  for (int i = tid; i < H_; i += 256){
    const float4* row = (const float4*)(fc2_w + (size_t)i * H_);
    float4 s4 = {0.f, 0.f, 0.f, 0.f};
    for (int j = 0; j < H_ / 4; ++j){
      float4 wv = row[j];
      s4.x += wv.x * h1[4 * j];     s4.y += wv.y * h1[4 * j + 1];
      s4.z += wv.z * h1[4 * j + 2]; s4.w += wv.w * h1[4 * j + 3];
    }
    out2[(size_t)b * H_ + i] = fmaxf(fc2_b[i] + s4.x + s4.y + s4.z + s4.w, 0.f);
  }
}

// ---------------- k_probs_hT: one wave per s-row group, bf16 reads ----------
__global__ __launch_bounds__(256) void k_probs_hT(
    const unsigned short* __restrict__ hT, const float* __restrict__ v_ptr,
    const float* __restrict__ out2, float* __restrict__ probs)
{
  const int tid = threadIdx.x, w = tid >> 6, l = tid & 63;
  const int b = blockIdx.y, s0 = blockIdx.x * 64;

  float vp[8], ob[8];
  {
    float4 a = *(const float4*)(v_ptr + l * 8);
    float4 c = *(const float4*)(v_ptr + l * 8 + 4);
    vp[0]=a.x; vp[1]=a.y; vp[2]=a.z; vp[3]=a.w;
    vp[4]=c.x; vp[5]=c.y; vp[6]=c.z; vp[7]=c.w;
    float4 d = *(const float4*)(out2 + (size_t)b * H_ + l * 8);
    float4 e = *(const float4*)(out2 + (size_t)b * H_ + l * 8 + 4);
    ob[0]=d.x; ob[1]=d.y; ob[2]=d.z; ob[3]=d.w;
    ob[4]=e.x; ob[5]=e.y; ob[6]=e.z; ob[7]=e.w;
  }

  const unsigned short* base = hT + (size_t)(b * S_ + s0) * H_ + l * 8;
  #pragma unroll 2
  for (int i = 0; i < 16; ++i){
    const int s = w * 16 + i;
    bf16x8 hv = __builtin_nontemporal_load((const bf16x8*)(base + (size_t)s * H_));
    float acc = 0.f;
    #pragma unroll
    for (int j = 0; j < 8; ++j)
      acc += vp[j] * fast_tanh(bf2f((unsigned short)hv[j]) + ob[j]);
    acc += __shfl_xor(acc, 1);  acc += __shfl_xor(acc, 2);
    acc += __shfl_xor(acc, 4);  acc += __shfl_xor(acc, 8);
    acc += __shfl_xor(acc, 16); acc += __shfl_xor(acc, 32);
    if (l == 0) probs[(size_t)b * S_ + s0 + s] = acc;
  }
}

// ---------------- k_probs_f32: fallback ------------------------------------
__global__ __launch_bounds__(256) void k_probs_f32(
    const float* __restrict__ hidden, const float* __restrict__ v_ptr,
    const float* __restrict__ out2, float* __restrict__ probs)
{
  __shared__ float vp[H_], ob[H_];
  const int b = blockIdx.y, c = blockIdx.x, tid = threadIdx.x;
  vp[tid]       = v_ptr[tid];
  vp[tid + 256] = v_ptr[tid + 256];
  ob[tid]       = out2[(size_t)b * H_ + tid];
  ob[tid + 256] = out2[(size_t)b * H_ + tid + 256];
  __syncthreads();

  const int s = c * 512 + tid * 2;
  const float* base = hidden + (size_t)b * H_ * S_ + s;
  float a0 = 0.f, a1 = 0.f;
  #pragma unroll 4
  for (int h = 0; h < H_; ++h){
    float2 hv = *(const float2*)(base + (size_t)h * S_);
    float wv = vp[h], o = ob[h];
    a0 += wv * fast_tanh(hv.x + o);
    a1 += wv * fast_tanh(hv.y + o);
  }
  probs[(size_t)b * S_ + s]     = a0;
  probs[(size_t)b * S_ + s + 1] = a1;
}

// ---------------- launcher ----------------
extern "C" void kernel_launch(void* const* d_in, const int* in_sizes, int n_in,
                              void* d_out, int out_size, void* d_ws, size_t ws_size,
                              hipStream_t stream)
{
  const float* hidden = (const float*)d_in[0];
  const float* v_att  = (const float*)d_in[1];
  const float* W_att  = (const float*)d_in[2];
  const float* v_ptr  = (const float*)d_in[3];
  const float* fc1_w  = (const float*)d_in[4];
  const float* fc1_b  = (const float*)d_in[5];
  const float* fc2_w  = (const float*)d_in[6];
  const float* fc2_b  = (const float*)d_in[7];
  float* probs = (float*)d_out;

  char* ws = (char*)d_ws;
  unsigned short* Wb = (unsigned short*)ws;                        // 512 KiB
  float* part_m   = (float*)(ws + (512u<<10));                     // 16 KiB
  float* part_z   = (float*)(ws + (512u<<10) + (16u<<10));         // 16 KiB
  float* part_ctx = (float*)(ws + (512u<<10) + (32u<<10));         // 8 MiB
  float* out2     = (float*)(ws + (512u<<10) + (32u<<10) + (8u<<20)); // 256 KiB
  unsigned short* hT = (unsigned short*)(ws + (16u<<20));          // 256 MiB

  const size_t need = (16u<<20) + ((size_t)B_ * S_ * H_ * 2);

  hipLaunchKernelGGL(k_convW, dim3(256), dim3(256), 0, stream, W_att, Wb);

  if (ws_size >= need){
    hipLaunchKernelGGL(k_pass1<1>, dim3(B_ * NP), dim3(512), 0, stream,
                       hidden, v_att, Wb, part_m, part_z, part_ctx, hT);
    hipLaunchKernelGGL(k_mlp, dim3(B_), dim3(256), 0, stream,
                       part_m, part_z, part_ctx, fc1_w, fc1_b, fc2_w, fc2_b, out2);
    hipLaunchKernelGGL(k_probs_hT, dim3(S_/64, B_), dim3(256), 0, stream,
                       hT, v_ptr, out2, probs);
  } else {
    hipLaunchKernelGGL(k_pass1<0>, dim3(B_ * NP), dim3(512), 0, stream,
                       hidden, v_att, Wb, part_m, part_z, part_ctx, (unsigned short*)Wb);
    hipLaunchKernelGGL(k_mlp, dim3(B_), dim3(256), 0, stream,
                       part_m, part_z, part_ctx, fc1_w, fc1_b, fc2_w, fc2_b, out2);
    hipLaunchKernelGGL(k_probs_f32, dim3(4, B_), dim3(256), 0, stream,
                       hidden, v_ptr, out2, probs);
  }
}